// Round 16
// baseline (857.906 us; speedup 1.0000x reference)
//
#include <hip/hip_runtime.h>

typedef unsigned int uint;
typedef unsigned short ushort;

#define D 512
#define TBM 128    // M-tile
#define TBN 256    // N-tile
#define TBK 32     // K-step
#define CPAD 264   // padded C-tile row (ushorts)
#define CHUNK 16384  // rows per pipeline chunk (N/4)
#define NAGGB 2048   // agg blocks per chunk (8 nodes/block @ 512 thr)
#define NGEMB 256    // gemm blocks per chunk (128 m-tiles x 2 n-tiles)

typedef __attribute__((ext_vector_type(8))) short bf16x8;
typedef __attribute__((ext_vector_type(4))) float f32x4;

__device__ __forceinline__ ushort f2b(float f) {
  uint u = __builtin_bit_cast(uint, f);
  return (ushort)((u + 0x7FFFu + ((u >> 16) & 1u)) >> 16);  // RNE
}
__device__ __forceinline__ float b_lo(uint u) { return __builtin_bit_cast(float, u << 16); }
__device__ __forceinline__ float b_hi(uint u) { return __builtin_bit_cast(float, u & 0xFFFF0000u); }

// monotone float<->uint map: uint order == float order (for max via atomicMax)
__device__ __forceinline__ uint encf(float x) {
  uint u = __builtin_bit_cast(uint, x);
  return ((int)u >= 0) ? (u | 0x80000000u) : ~u;
}
__device__ __forceinline__ float decf(uint u) {
  return (u & 0x80000000u) ? __builtin_bit_cast(float, u ^ 0x80000000u)
                           : __builtin_bit_cast(float, ~u);
}

__device__ __forceinline__ void gload16(const void* g, void* l) {
  __builtin_amdgcn_global_load_lds((const __attribute__((address_space(1))) void*)g,
                                   (__attribute__((address_space(3))) void*)l, 16, 0, 0);
}

// ---- f32 -> bf16 convert + FUSED stage-0 segment-max (R13-verified) -------
__global__ __launch_bounds__(256) void f32_to_bf16_segmax(
    const float* __restrict__ in, ushort* __restrict__ out,
    const int* __restrict__ batch, uint* __restrict__ mv0) {
  const int t = threadIdx.x;
  const int chunk = t & 63;
  const int rsub = t >> 6;
  const int row0 = blockIdx.x * 128;
  float mx[8];
#pragma unroll
  for (int j = 0; j < 8; ++j) mx[j] = -3.4e38f;
  int curg = batch[row0 + rsub];
#pragma unroll 4
  for (int k = 0; k < 32; ++k) {
    const int row = row0 + rsub + k * 4;
    const int gg = batch[row];
    if (gg != curg) {
#pragma unroll
      for (int j = 0; j < 8; ++j)
        atomicMax(&mv0[(size_t)curg * D + chunk * 8 + j], encf(mx[j]));
#pragma unroll
      for (int j = 0; j < 8; ++j) mx[j] = -3.4e38f;
      curg = gg;
    }
    const float4* p = (const float4*)(in + (size_t)row * D + chunk * 8);
    const float4 a = p[0], b = p[1];
    float v[8] = {a.x, a.y, a.z, a.w, b.x, b.y, b.z, b.w};
    uint4 o;
    o.x = f2b(v[0]) | ((uint)f2b(v[1]) << 16);
    o.y = f2b(v[2]) | ((uint)f2b(v[3]) << 16);
    o.z = f2b(v[4]) | ((uint)f2b(v[5]) << 16);
    o.w = f2b(v[6]) | ((uint)f2b(v[7]) << 16);
    *(uint4*)(out + (size_t)row * D + chunk * 8) = o;
#pragma unroll
    for (int j = 0; j < 8; ++j) mx[j] = fmaxf(mx[j], v[j]);
  }
#pragma unroll
  for (int j = 0; j < 8; ++j)
    atomicMax(&mv0[(size_t)curg * D + chunk * 8 + j], encf(mx[j]));
}

// ---- transpose all 6 weight mats: 512x512 f32 [k][o] -> bf16 BT [o][k] ----
__global__ __launch_bounds__(256) void transpose_all(const float* __restrict__ lin1_w,
                                                     const float* __restrict__ lin2_w,
                                                     ushort* __restrict__ l1bt,
                                                     ushort* __restrict__ l2bt) {
  __shared__ float tile[64][65];
  const int z = blockIdx.z, l = z >> 1;
  const float* W = ((z & 1) ? lin2_w : lin1_w) + (size_t)l * D * D;
  ushort* BT = ((z & 1) ? l2bt : l1bt) + (size_t)l * D * D;
  const int bk = blockIdx.x * 64;  // k block
  const int bo = blockIdx.y * 64;  // o block
  const int tx = threadIdx.x & 63, ty = threadIdx.x >> 6;
#pragma unroll
  for (int r = 0; r < 64; r += 4)
    tile[r + ty][tx] = W[(size_t)(bk + r + ty) * D + bo + tx];
  __syncthreads();
#pragma unroll
  for (int r = 0; r < 64; r += 4)
    BT[(size_t)(bo + r + ty) * D + bk + tx] = f2b(tile[tx][r + ty]);
}

// ---------------------------- CSR build ------------------------------------
__global__ void count_deg(const int* __restrict__ dst, int* __restrict__ deg, int E) {
  const int e = blockIdx.x * 256 + threadIdx.x;
  if (e < E) atomicAdd(&deg[dst[e]], 1);
}

__global__ __launch_bounds__(256) void scan_block(const int* __restrict__ in,
                                                  int* __restrict__ out,
                                                  int* __restrict__ bsum) {
  __shared__ int sm[256];
  const int t = threadIdx.x;
  const int gi = blockIdx.x * 256 + t;
  const int v = in[gi];
  int x = v;
  sm[t] = x;
  __syncthreads();
#pragma unroll
  for (int off = 1; off < 256; off <<= 1) {
    const int y = (t >= off) ? sm[t - off] : 0;
    __syncthreads();
    x += y;
    sm[t] = x;
    __syncthreads();
  }
  out[gi] = x - v;  // exclusive
  if (t == 255 && bsum) bsum[blockIdx.x] = x;
}

__global__ void scan_fixup(int* __restrict__ rowptr, const int* __restrict__ bsum,
                           int* __restrict__ cursor, int N, int E) {
  const int i = blockIdx.x * 256 + threadIdx.x;
  const int r = rowptr[i] + bsum[i >> 8];
  rowptr[i] = r;
  cursor[i] = r;
  if (i == 0) rowptr[N] = E;
}

__global__ void fill_csr(const int* __restrict__ src, const int* __restrict__ dst,
                         int* __restrict__ cursor, int* __restrict__ csr, int E) {
  const int e = blockIdx.x * 256 + threadIdx.x;
  if (e >= E) return;
  const int pos = atomicAdd(&cursor[dst[e]], 1);
  csr[pos] = src[e];
}

// --------------- agg body: one wave aggregates one node --------------------
#define ACC8(v)                                          \
  a[0] += b_lo((v).x); a[1] += b_hi((v).x);              \
  a[2] += b_lo((v).y); a[3] += b_hi((v).y);              \
  a[4] += b_lo((v).z); a[5] += b_hi((v).z);              \
  a[6] += b_lo((v).w); a[7] += b_hi((v).w)

__device__ __forceinline__ void agg_node(int node, int lane,
                                         const ushort* __restrict__ xb,
                                         const int* __restrict__ rowptr,
                                         const int* __restrict__ csr, float sc,
                                         ushort* __restrict__ h) {
  const size_t off = (size_t)lane * 8;
  const size_t base = (size_t)node * D + off;
  const uint4 u = *(const uint4*)(xb + base);
  float a[8];
  a[0] = b_lo(u.x) * sc; a[1] = b_hi(u.x) * sc;
  a[2] = b_lo(u.y) * sc; a[3] = b_hi(u.y) * sc;
  a[4] = b_lo(u.z) * sc; a[5] = b_hi(u.z) * sc;
  a[6] = b_lo(u.w) * sc; a[7] = b_hi(u.w) * sc;
  int e = rowptr[node];
  const int en = rowptr[node + 1];
  for (; e + 4 <= en; e += 4) {
    const int s0 = csr[e], s1 = csr[e + 1], s2 = csr[e + 2], s3 = csr[e + 3];
    const uint4 v0 = *(const uint4*)(xb + (size_t)s0 * D + off);
    const uint4 v1 = *(const uint4*)(xb + (size_t)s1 * D + off);
    const uint4 v2 = *(const uint4*)(xb + (size_t)s2 * D + off);
    const uint4 v3 = *(const uint4*)(xb + (size_t)s3 * D + off);
    ACC8(v0); ACC8(v1); ACC8(v2); ACC8(v3);
  }
  if (e + 2 <= en) {
    const int s0 = csr[e], s1 = csr[e + 1];
    const uint4 v0 = *(const uint4*)(xb + (size_t)s0 * D + off);
    const uint4 v1 = *(const uint4*)(xb + (size_t)s1 * D + off);
    ACC8(v0); ACC8(v1);
    e += 2;
  }
  if (e < en) {
    const uint4 v0 = *(const uint4*)(xb + (size_t)csr[e] * D + off);
    ACC8(v0);
  }
  uint4 o;
  o.x = f2b(a[0]) | ((uint)f2b(a[1]) << 16);
  o.y = f2b(a[2]) | ((uint)f2b(a[3]) << 16);
  o.z = f2b(a[4]) | ((uint)f2b(a[5]) << 16);
  o.w = f2b(a[6]) | ((uint)f2b(a[7]) << 16);
  *(uint4*)(h + base) = o;
}

// ------ GEMM tile body (R15-verified): O = leaky(A @ BT^T + bias) ----------
// 128x256 tile, BK=32, 3-buffer 2-ahead counted vmcnt, parity-correct
// chunk-XOR swizzle, padded-LDS epilogue, optional fused segmax.
__device__ __forceinline__ void gemm_tile(
    ushort* smem, int gb, int nG, size_t mBase,
    const ushort* __restrict__ A, const ushort* __restrict__ BT,
    const float* __restrict__ bias, ushort* __restrict__ Obf,
    float* __restrict__ Of32, const int* __restrict__ batch,
    uint* __restrict__ mvstage) {
  ushort* const lA0 = smem;
  ushort* const lB0 = smem + 4096;
  ushort* const lA1 = smem + 12288;
  ushort* const lB1 = smem + 16384;
  ushort* const lA2 = smem + 24576;
  ushort* const lB2 = smem + 28672;

  const int tid = threadIdx.x;
  const int lane = tid & 63;
  const int wave = tid >> 6;
  const int wr = wave >> 2, wc = wave & 3;  // 2x4 waves; 64x64 out each

  // XCD swizzle over this role's local block ids (nG divisible by 8):
  const int wg = (gb & 7) * (nG >> 3) + (gb >> 3);
  const int n0 = (wg & 1) * TBN;
  const size_t m0 = mBase + (size_t)(wg >> 1) * TBM;

  const int srow = tid >> 2;                              // 0..127
  const int schunk = ((tid & 3) ^ ((tid >> 3) & 3)) * 8;  // parity-key swizzled

  f32x4 acc[4][4] = {};

  const int rsel = lane & 15;
  const int g = lane >> 4;
  const int ch = (g ^ ((rsel >> 1) & 3)) * 8;

#define STAGE(bufA, bufB, kt)                                                    \
  {                                                                              \
    const int k0_ = (kt) * TBK;                                                  \
    gload16(A + (m0 + srow) * D + k0_ + schunk, &(bufA)[tid * 8]);               \
    gload16(BT + (size_t)(n0 + srow) * D + k0_ + schunk, &(bufB)[tid * 8]);      \
    gload16(BT + (size_t)(n0 + 128 + srow) * D + k0_ + schunk,                   \
            &(bufB)[(512 + tid) * 8]);                                           \
  }

#define COMPUTE(bufA, bufB)                                                      \
  {                                                                              \
    __builtin_amdgcn_s_setprio(1);                                               \
    bf16x8 af_[4], bf_[4];                                                       \
    _Pragma("unroll") for (int j_ = 0; j_ < 4; ++j_)                             \
        bf_[j_] = *(const bf16x8*)&(bufB)[(wc * 64 + j_ * 16 + rsel) * TBK + ch];\
    _Pragma("unroll") for (int i_ = 0; i_ < 4; ++i_)                             \
        af_[i_] = *(const bf16x8*)&(bufA)[(wr * 64 + i_ * 16 + rsel) * TBK + ch];\
    _Pragma("unroll") for (int i_ = 0; i_ < 4; ++i_)                             \
        _Pragma("unroll") for (int j_ = 0; j_ < 4; ++j_)                         \
            acc[i_][j_] = __builtin_amdgcn_mfma_f32_16x16x32_bf16(               \
                af_[i_], bf_[j_], acc[i_][j_], 0, 0, 0);                         \
    __builtin_amdgcn_s_setprio(0);                                               \
  }

#define VMW(N)                                              \
  asm volatile("s_waitcnt vmcnt(" #N ")" ::: "memory");     \
  __builtin_amdgcn_sched_barrier(0)
#define BAR() __builtin_amdgcn_s_barrier()

  STAGE(lA0, lB0, 0); STAGE(lA1, lB1, 1); STAGE(lA2, lB2, 2);
  VMW(6); BAR(); COMPUTE(lA0, lB0); BAR(); STAGE(lA0, lB0, 3);
  VMW(6); BAR(); COMPUTE(lA1, lB1); BAR(); STAGE(lA1, lB1, 4);
  VMW(6); BAR(); COMPUTE(lA2, lB2); BAR(); STAGE(lA2, lB2, 5);
  VMW(6); BAR(); COMPUTE(lA0, lB0); BAR(); STAGE(lA0, lB0, 6);
  VMW(6); BAR(); COMPUTE(lA1, lB1); BAR(); STAGE(lA1, lB1, 7);
  VMW(6); BAR(); COMPUTE(lA2, lB2); BAR(); STAGE(lA2, lB2, 8);
  VMW(6); BAR(); COMPUTE(lA0, lB0); BAR(); STAGE(lA0, lB0, 9);
  VMW(6); BAR(); COMPUTE(lA1, lB1); BAR(); STAGE(lA1, lB1, 10);
  VMW(6); BAR(); COMPUTE(lA2, lB2); BAR(); STAGE(lA2, lB2, 11);
  VMW(6); BAR(); COMPUTE(lA0, lB0); BAR(); STAGE(lA0, lB0, 12);
  VMW(6); BAR(); COMPUTE(lA1, lB1); BAR(); STAGE(lA1, lB1, 13);
  VMW(6); BAR(); COMPUTE(lA2, lB2); BAR(); STAGE(lA2, lB2, 14);
  VMW(6); BAR(); COMPUTE(lA0, lB0); BAR(); STAGE(lA0, lB0, 15);
  VMW(6); BAR(); COMPUTE(lA1, lB1); BAR();
  VMW(3); BAR(); COMPUTE(lA2, lB2); BAR();
  VMW(0); BAR(); COMPUTE(lA0, lB0);
#undef STAGE
#undef COMPUTE
#undef VMW
#undef BAR

  __syncthreads();

  const int rbase = g * 4;
#pragma unroll
  for (int h = 0; h < 2; ++h) {
    if (wr == h) {
#pragma unroll
      for (int j = 0; j < 4; ++j) {
        const int col = wc * 64 + j * 16 + rsel;
        const float bv = bias[n0 + col];
#pragma unroll
        for (int i = 0; i < 4; ++i) {
#pragma unroll
          for (int q = 0; q < 4; ++q) {
            const int lrow = i * 16 + rbase + q;  // 0..63
            float v = acc[i][j][q] + bv;
            v = (v > 0.f) ? v : 0.01f * v;
            smem[lrow * CPAD + col] = f2b(v);
          }
        }
      }
    }
    __syncthreads();
#pragma unroll
    for (int it = 0; it < 4; ++it) {
      const int slot = it * 512 + tid;  // 2048 slots
      const int row = slot >> 5;
      const int chunk = slot & 31;
      const uint4 vv = *(const uint4*)&smem[row * CPAD + chunk * 8];
      const size_t grow = m0 + h * 64 + row;
      if (Obf) *(uint4*)(Obf + grow * D + n0 + chunk * 8) = vv;
      if (Of32) {
        float4 f0, f1;
        f0.x = b_lo(vv.x); f0.y = b_hi(vv.x); f0.z = b_lo(vv.y); f0.w = b_hi(vv.y);
        f1.x = b_lo(vv.z); f1.y = b_hi(vv.z); f1.z = b_lo(vv.w); f1.w = b_hi(vv.w);
        float* op = Of32 + grow * D + n0 + chunk * 8;
        *(float4*)op = f0;
        *(float4*)(op + 4) = f1;
      }
    }
    if (mvstage) {
      const int col = tid & 255;
      const int rh = tid >> 8;
      const size_t rowbase = m0 + h * 64 + rh * 32;
      float mx = -3.4e38f;
      int curg = batch[rowbase];
#pragma unroll 4
      for (int r = 0; r < 32; ++r) {
        const int gg = batch[rowbase + r];
        if (gg != curg) {
          atomicMax(&mvstage[(size_t)curg * D + n0 + col], encf(mx));
          mx = -3.4e38f;
          curg = gg;
        }
        mx = fmaxf(mx, b_lo((uint)smem[(rh * 32 + r) * CPAD + col]));
      }
      atomicMax(&mvstage[(size_t)curg * D + n0 + col], encf(mx));
    }
    __syncthreads();
  }
}

// ---- fat pipelined layer kernel: agg(cAgg) || G1(cG1) || G2(cG2) ----------
// R16: agg is latency-bound (0 MFMA), GEMM is stall-bound (idle mem pipes);
// running them as SEPARATE BLOCKS in one grid overlaps them on each CU
// (m114 mechanism — unlike R7's intra-block lockstep). Bresenham interleave
// spreads gemm blocks through the index space so each CU's 2 resident blocks
// mix roles. Buffers: agg P->H[cAgg]; G1 H[cG1]->T[cG1]; G2 T[cG2]->H[cG2]
// (or xout f32 on last layer) — all row ranges disjoint per launch.
__global__ __launch_bounds__(512, 4) void fat_layer(
    const ushort* __restrict__ P, ushort* __restrict__ H, ushort* __restrict__ T,
    const int* __restrict__ rowptr, const int* __restrict__ csr,
    const float* __restrict__ eps_arr, int layer,
    const ushort* __restrict__ W1T, const float* __restrict__ b1,
    const ushort* __restrict__ W2T, const float* __restrict__ b2,
    const int* __restrict__ batch, uint* __restrict__ mvstage,
    float* __restrict__ xoutf, int lastLayer,
    int nG1, int nG2, int nAgg, int cG1, int cG2, int cAgg) {
  __shared__ alignas(16) ushort smem[36864];  // 72 KB (GEMM roles only)
  const int bid = blockIdx.x;
  const int ng = nG1 + nG2;
  const int tot = ng + nAgg;
  const int gcount = (int)(((long long)bid * ng) / tot);
  const bool isg = ((((long long)(bid + 1)) * ng) / tot) > gcount;
  if (isg) {
    if (gcount < nG1) {
      gemm_tile(smem, gcount, nG1, (size_t)cG1 * CHUNK, H, W1T, b1,
                T, nullptr, batch, nullptr);
    } else {
      gemm_tile(smem, gcount - nG1, nG2, (size_t)cG2 * CHUNK, T, W2T, b2,
                lastLayer ? nullptr : H, lastLayer ? xoutf : nullptr,
                batch, mvstage);
    }
  } else {
    const int aidx = bid - gcount;
    const int node = cAgg * CHUNK + aidx * 8 + (threadIdx.x >> 6);
    agg_node(node, threadIdx.x & 63, P, rowptr, csr, 1.0f + eps_arr[layer], H);
  }
}

// ------------- pool projection, split-K (R10-verified); mv is ENCODED ------
__global__ __launch_bounds__(256) void pool_partial(
    const uint* __restrict__ mv, const float* __restrict__ proj_w,
    const float* __restrict__ pool_w, float* __restrict__ pp) {
  const int g = blockIdx.x;                      // 64
  const int o = blockIdx.y * 256 + threadIdx.x;  // 2 x 256
  const int s = blockIdx.z >> 2, kq = blockIdx.z & 3;
  const float* W = (s == 0) ? proj_w : pool_w + (size_t)(s - 1) * D * D;
  const uint* m = mv + ((size_t)s * 64 + g) * D + kq * 128;
  const float* Wp = W + (size_t)(kq * 128) * D + o;
  float acc = 0.f;
#pragma unroll 8
  for (int k = 0; k < 128; ++k) acc = fmaf(decf(m[k]), Wp[(size_t)k * D], acc);
  pp[((size_t)blockIdx.z * 64 + g) * D + o] = acc;
}

__global__ __launch_bounds__(256) void pool_reduce(
    const float* __restrict__ pp, const float* __restrict__ proj_b,
    const float* __restrict__ pool_b, float* __restrict__ part) {
  const int i = blockIdx.x * 256 + threadIdx.x;  // < 64*512
  const int g = i >> 9, o = i & (D - 1);
  float acc = proj_b[o] + pool_b[o] + pool_b[D + o] + pool_b[2 * D + o];
#pragma unroll
  for (int s = 0; s < 16; ++s) acc += pp[((size_t)s * 64 + g) * D + o];
  part[i] = acc;
}

// ---------------------------------------------------------------------------
extern "C" void kernel_launch(void* const* d_in, const int* in_sizes, int n_in,
                              void* d_out, int out_size, void* d_ws, size_t ws_size,
                              hipStream_t stream) {
  const float* x = (const float*)d_in[0];
  const int* ei = (const int*)d_in[1];
  const int* batch = (const int*)d_in[2];
  const float* proj_w = (const float*)d_in[3];
  const float* proj_b = (const float*)d_in[4];
  const float* lin1_w = (const float*)d_in[5];
  const float* lin1_b = (const float*)d_in[6];
  const float* lin2_w = (const float*)d_in[7];
  const float* lin2_b = (const float*)d_in[8];
  const float* eps = (const float*)d_in[9];
  const float* pool_w = (const float*)d_in[10];
  const float* pool_b = (const float*)d_in[11];

  const int N = in_sizes[0] / D;  // 65536
  const int E = in_sizes[1] / 2;  // 524288
  const int B = 64;
  const int* src = ei;
  const int* dst = ei + E;

  float* part = (float*)d_out;         // [64][512]
  float* xout = part + (size_t)B * D;  // [N][512]

  // workspace carve (~212 MB)
  char* w = (char*)d_ws;
  ushort* xb = (ushort*)w;   w += (size_t)N * D * 2;
  ushort* hb = (ushort*)w;   w += (size_t)N * D * 2;
  ushort* tb = (ushort*)w;   w += (size_t)N * D * 2;
  ushort* l1bt = (ushort*)w; w += (size_t)3 * D * D * 2;
  ushort* l2bt = (ushort*)w; w += (size_t)3 * D * D * 2;
  int* rowptr = (int*)w;     w += (size_t)(N + 4) * 4;
  int* cursor = (int*)w;     w += (size_t)N * 4;
  int* deg = (int*)w;        w += (size_t)N * 4;
  int* csr = (int*)w;        w += (size_t)E * 4;
  int* bsum = (int*)w;       w += 256 * 4;
  int* gstart = (int*)w;     w += 128 * 4;
  uint* mvall = (uint*)w;     w += (size_t)4 * B * D * 4;   // [4][64][512] encoded
  float* pp = (float*)w;      w += (size_t)16 * B * D * 4;  // [16][64][512]
  (void)ws_size; (void)n_in; (void)out_size; (void)gstart;

  (void)hipMemsetAsync(deg, 0, (size_t)N * 4, stream);
  (void)hipMemsetAsync(mvall, 0, (size_t)4 * B * D * 4, stream);
  // convert + fused stage-0 segmax
  f32_to_bf16_segmax<<<N / 128, 256, 0, stream>>>(x, xb, batch, mvall);
  transpose_all<<<dim3(8, 8, 6), 256, 0, stream>>>(lin1_w, lin2_w, l1bt, l2bt);
  count_deg<<<(E + 255) / 256, 256, 0, stream>>>(dst, deg, E);
  scan_block<<<N / 256, 256, 0, stream>>>(deg, rowptr, bsum);
  scan_block<<<1, 256, 0, stream>>>(bsum, bsum, (int*)nullptr);
  scan_fixup<<<N / 256, 256, 0, stream>>>(rowptr, bsum, cursor, N, E);
  fill_csr<<<(E + 255) / 256, 256, 0, stream>>>(src, dst, cursor, csr, E);

  // pipelined layers: 6 fat launches each; buffers rotate P<->H, T shared.
  ushort* P = xb;
  ushort* H = hb;
  for (int l = 0; l < 3; ++l) {
    const int last = (l == 2);
    const ushort* W1 = l1bt + (size_t)l * D * D;
    const ushort* W2 = l2bt + (size_t)l * D * D;
    const float* bb1 = lin1_b + (size_t)l * D;
    const float* bb2 = lin2_b + (size_t)l * D;
    uint* mvs = mvall + (size_t)(l + 1) * B * D;
#define FAT(ng1, ng2, nagg, cg1, cg2, cagg)                                   \
  fat_layer<<<(ng1) + (ng2) + (nagg), 512, 0, stream>>>(                      \
      P, H, tb, rowptr, csr, eps, l, W1, bb1, W2, bb2, batch, mvs, xout,      \
      last, (ng1), (ng2), (nagg), (cg1), (cg2), (cagg))
    FAT(0,     0,     NAGGB, 0, 0, 0);  // s0: agg(c0)
    FAT(NGEMB, 0,     NAGGB, 0, 0, 1);  // s1: G1(c0) || agg(c1)
    FAT(NGEMB, NGEMB, NAGGB, 1, 0, 2);  // s2: G1(c1) || G2(c0) || agg(c2)
    FAT(NGEMB, NGEMB, NAGGB, 2, 1, 3);  // s3: G1(c2) || G2(c1) || agg(c3)
    FAT(NGEMB, NGEMB, 0,     3, 2, 0);  // s4: G1(c3) || G2(c2)
    FAT(0,     NGEMB, 0,     0, 3, 0);  // s5: G2(c3)
#undef FAT
    ushort* tmp = P; P = H; H = tmp;  // next layer input = this layer's G2 out
  }

  // split-K pool projection (decodes mvall)
  pool_partial<<<dim3(B, 2, 16), 256, 0, stream>>>(mvall, proj_w, pool_w, pp);
  pool_reduce<<<B * D / 256, 256, 0, stream>>>(pp, proj_b, pool_b, part);
}

// Round 17
// 718.451 us; speedup vs baseline: 1.1941x; 1.1941x over previous
//
#include <hip/hip_runtime.h>

typedef unsigned int uint;
typedef unsigned short ushort;

#define D 512
#define TBM 128   // M-tile
#define TBN 256   // N-tile
#define TBK 32    // K-step
#define CPAD 264  // padded C-tile row (ushorts)

typedef __attribute__((ext_vector_type(8))) short bf16x8;
typedef __attribute__((ext_vector_type(4))) float f32x4;

__device__ __forceinline__ ushort f2b(float f) {
  uint u = __builtin_bit_cast(uint, f);
  return (ushort)((u + 0x7FFFu + ((u >> 16) & 1u)) >> 16);  // RNE
}
__device__ __forceinline__ float b_lo(uint u) { return __builtin_bit_cast(float, u << 16); }
__device__ __forceinline__ float b_hi(uint u) { return __builtin_bit_cast(float, u & 0xFFFF0000u); }

// monotone float<->uint map: uint order == float order (for max via atomicMax)
__device__ __forceinline__ uint encf(float x) {
  uint u = __builtin_bit_cast(uint, x);
  return ((int)u >= 0) ? (u | 0x80000000u) : ~u;
}
__device__ __forceinline__ float decf(uint u) {
  return (u & 0x80000000u) ? __builtin_bit_cast(float, u ^ 0x80000000u)
                           : __builtin_bit_cast(float, ~u);
}

__device__ __forceinline__ void gload16(const void* g, void* l) {
  __builtin_amdgcn_global_load_lds((const __attribute__((address_space(1))) void*)g,
                                   (__attribute__((address_space(3))) void*)l, 16, 0, 0);
}

// ---- f32 -> bf16 convert + FUSED stage-0 segment-max ----------------------
// R17 re-grid: R13's 512-block version measured 82.8us at 18.5% occupancy
// (latency-bound). Now 1024 blocks x 512 thr (64 rows/block) -> 100% occ.
// Blocks fully inside one graph (~94%: 63 boundaries / 1024 blocks) combine
// partials in LDS (b128 writes, conflict-free) and emit 1 atomic/column;
// boundary blocks fall back to per-thread encoded-atomicMax flush (R13 path).
__global__ __launch_bounds__(512) void f32_to_bf16_segmax(
    const float* __restrict__ in, ushort* __restrict__ out,
    const int* __restrict__ batch, uint* __restrict__ mv0) {
  __shared__ uint red[8 * 512];  // 16 KB
  const int t = threadIdx.x;
  const int chunk = t & 63;   // 8 cols: [chunk*8, chunk*8+8)
  const int rsub = t >> 6;    // 0..7
  const int row0 = blockIdx.x * 64;
  const bool uni = (batch[row0] == batch[row0 + 63]);  // sorted batch
  float mx[8];
#pragma unroll
  for (int j = 0; j < 8; ++j) mx[j] = -3.4e38f;
  int curg = batch[row0 + rsub];
#pragma unroll
  for (int k = 0; k < 8; ++k) {
    const int row = row0 + rsub + k * 8;  // wave reads a full 2KB row
    if (!uni) {
      const int gg = batch[row];
      if (gg != curg) {
#pragma unroll
        for (int j = 0; j < 8; ++j)
          atomicMax(&mv0[(size_t)curg * D + chunk * 8 + j], encf(mx[j]));
#pragma unroll
        for (int j = 0; j < 8; ++j) mx[j] = -3.4e38f;
        curg = gg;
      }
    }
    const float4* p = (const float4*)(in + (size_t)row * D + chunk * 8);
    const float4 a = p[0], b = p[1];
    float v[8] = {a.x, a.y, a.z, a.w, b.x, b.y, b.z, b.w};
    uint4 o;
    o.x = f2b(v[0]) | ((uint)f2b(v[1]) << 16);
    o.y = f2b(v[2]) | ((uint)f2b(v[3]) << 16);
    o.z = f2b(v[4]) | ((uint)f2b(v[5]) << 16);
    o.w = f2b(v[6]) | ((uint)f2b(v[7]) << 16);
    *(uint4*)(out + (size_t)row * D + chunk * 8) = o;
#pragma unroll
    for (int j = 0; j < 8; ++j) mx[j] = fmaxf(mx[j], v[j]);
  }
  if (uni) {
    // LDS combine: b128 writes (wave-contiguous), then col-owner reduces.
    uint4 e0, e1;
    e0.x = encf(mx[0]); e0.y = encf(mx[1]); e0.z = encf(mx[2]); e0.w = encf(mx[3]);
    e1.x = encf(mx[4]); e1.y = encf(mx[5]); e1.z = encf(mx[6]); e1.w = encf(mx[7]);
    *(uint4*)&red[rsub * 512 + chunk * 8] = e0;
    *(uint4*)&red[rsub * 512 + chunk * 8 + 4] = e1;
    __syncthreads();
    uint m = red[t];  // col t
#pragma unroll
    for (int r = 1; r < 8; ++r) m = max(m, red[r * 512 + t]);
    atomicMax(&mv0[(size_t)curg * D + t], m);
  } else {
#pragma unroll
    for (int j = 0; j < 8; ++j)
      atomicMax(&mv0[(size_t)curg * D + chunk * 8 + j], encf(mx[j]));
  }
}

// ---- transpose all 6 weight mats: 512x512 f32 [k][o] -> bf16 BT [o][k] ----
__global__ __launch_bounds__(256) void transpose_all(const float* __restrict__ lin1_w,
                                                     const float* __restrict__ lin2_w,
                                                     ushort* __restrict__ l1bt,
                                                     ushort* __restrict__ l2bt) {
  __shared__ float tile[64][65];
  const int z = blockIdx.z, l = z >> 1;
  const float* W = ((z & 1) ? lin2_w : lin1_w) + (size_t)l * D * D;
  ushort* BT = ((z & 1) ? l2bt : l1bt) + (size_t)l * D * D;
  const int bk = blockIdx.x * 64;  // k block
  const int bo = blockIdx.y * 64;  // o block
  const int tx = threadIdx.x & 63, ty = threadIdx.x >> 6;
#pragma unroll
  for (int r = 0; r < 64; r += 4)
    tile[r + ty][tx] = W[(size_t)(bk + r + ty) * D + bo + tx];
  __syncthreads();
#pragma unroll
  for (int r = 0; r < 64; r += 4)
    BT[(size_t)(bo + r + ty) * D + bk + tx] = f2b(tile[tx][r + ty]);
}

// ---------------------------- CSR build ------------------------------------
__global__ void count_deg(const int* __restrict__ dst, int* __restrict__ deg, int E) {
  const int e = blockIdx.x * 256 + threadIdx.x;
  if (e < E) atomicAdd(&deg[dst[e]], 1);
}

__global__ __launch_bounds__(256) void scan_block(const int* __restrict__ in,
                                                  int* __restrict__ out,
                                                  int* __restrict__ bsum) {
  __shared__ int sm[256];
  const int t = threadIdx.x;
  const int gi = blockIdx.x * 256 + t;
  const int v = in[gi];
  int x = v;
  sm[t] = x;
  __syncthreads();
#pragma unroll
  for (int off = 1; off < 256; off <<= 1) {
    const int y = (t >= off) ? sm[t - off] : 0;
    __syncthreads();
    x += y;
    sm[t] = x;
    __syncthreads();
  }
  out[gi] = x - v;  // exclusive
  if (t == 255 && bsum) bsum[blockIdx.x] = x;
}

__global__ void scan_fixup(int* __restrict__ rowptr, const int* __restrict__ bsum,
                           int* __restrict__ cursor, int N, int E) {
  const int i = blockIdx.x * 256 + threadIdx.x;
  const int r = rowptr[i] + bsum[i >> 8];
  rowptr[i] = r;
  cursor[i] = r;
  if (i == 0) rowptr[N] = E;
}

__global__ void fill_csr(const int* __restrict__ src, const int* __restrict__ dst,
                         int* __restrict__ cursor, int* __restrict__ csr, int E) {
  const int e = blockIdx.x * 256 + threadIdx.x;
  if (e >= E) return;
  const int pos = atomicAdd(&cursor[dst[e]], 1);
  csr[pos] = src[e];
}

// --------------- GIN aggregation: h = (1+eps)*x + sum_nbr x ----------------
// At its random-gather structural floor (R2/R4/R7/R16 evidence). Do not touch.
#define ACC8(v)                                          \
  a[0] += b_lo((v).x); a[1] += b_hi((v).x);              \
  a[2] += b_lo((v).y); a[3] += b_hi((v).y);              \
  a[4] += b_lo((v).z); a[5] += b_hi((v).z);              \
  a[6] += b_lo((v).w); a[7] += b_hi((v).w)

__global__ __launch_bounds__(256) void agg_kernel(const ushort* __restrict__ xb,
                                                  const int* __restrict__ rowptr,
                                                  const int* __restrict__ csr,
                                                  const float* __restrict__ eps_arr,
                                                  int layer, ushort* __restrict__ h) {
  const int node = blockIdx.x * 4 + (threadIdx.x >> 6);
  const int lane = threadIdx.x & 63;
  const float sc = 1.0f + eps_arr[layer];
  const size_t off = (size_t)lane * 8;
  const size_t base = (size_t)node * D + off;
  const uint4 u = *(const uint4*)(xb + base);
  float a[8];
  a[0] = b_lo(u.x) * sc; a[1] = b_hi(u.x) * sc;
  a[2] = b_lo(u.y) * sc; a[3] = b_hi(u.y) * sc;
  a[4] = b_lo(u.z) * sc; a[5] = b_hi(u.z) * sc;
  a[6] = b_lo(u.w) * sc; a[7] = b_hi(u.w) * sc;
  int e = rowptr[node];
  const int en = rowptr[node + 1];
  for (; e + 4 <= en; e += 4) {
    const int s0 = csr[e], s1 = csr[e + 1], s2 = csr[e + 2], s3 = csr[e + 3];
    const uint4 v0 = *(const uint4*)(xb + (size_t)s0 * D + off);
    const uint4 v1 = *(const uint4*)(xb + (size_t)s1 * D + off);
    const uint4 v2 = *(const uint4*)(xb + (size_t)s2 * D + off);
    const uint4 v3 = *(const uint4*)(xb + (size_t)s3 * D + off);
    ACC8(v0); ACC8(v1); ACC8(v2); ACC8(v3);
  }
  if (e + 2 <= en) {
    const int s0 = csr[e], s1 = csr[e + 1];
    const uint4 v0 = *(const uint4*)(xb + (size_t)s0 * D + off);
    const uint4 v1 = *(const uint4*)(xb + (size_t)s1 * D + off);
    ACC8(v0); ACC8(v1);
    e += 2;
  }
  if (e < en) {
    const uint4 v0 = *(const uint4*)(xb + (size_t)csr[e] * D + off);
    ACC8(v0);
  }
  uint4 o;
  o.x = f2b(a[0]) | ((uint)f2b(a[1]) << 16);
  o.y = f2b(a[2]) | ((uint)f2b(a[3]) << 16);
  o.z = f2b(a[4]) | ((uint)f2b(a[5]) << 16);
  o.w = f2b(a[6]) | ((uint)f2b(a[7]) << 16);
  *(uint4*)(h + base) = o;
}

// ------ bf16 GEMM: O = leaky(A @ BT^T + bias), 128x256 tile, BK=32 ---------
// R15-verified: 2 blocks/CU, 3-buffer 2-ahead counted vmcnt, parity-correct
// chunk-XOR swizzle (key (rsel>>1)&3 both sides), padded-LDS epilogue,
// nullable Obf/Of32, fused segmax. (R16 fat-kernel pipelining: reverted —
// uniform 72KB LDS footprint starved the agg role; +130us.)
__global__ __launch_bounds__(512, 4) void gemm_bias_leaky(
    const ushort* __restrict__ A, const ushort* __restrict__ BT,
    const float* __restrict__ bias, ushort* __restrict__ Obf,
    float* __restrict__ Of32, const int* __restrict__ batch,
    uint* __restrict__ mvstage) {
  __shared__ alignas(16) ushort smem[36864];  // 72 KB
  ushort* const lA0 = smem;            // [128][32]  4096
  ushort* const lB0 = smem + 4096;     // [256][32]  8192
  ushort* const lA1 = smem + 12288;
  ushort* const lB1 = smem + 16384;
  ushort* const lA2 = smem + 24576;
  ushort* const lB2 = smem + 28672;

  const int tid = threadIdx.x;
  const int lane = tid & 63;
  const int wave = tid >> 6;
  const int wr = wave >> 2, wc = wave & 3;  // 2x4 waves; 64x64 out each

  // XCD swizzle (nwg = 2*512 = 1024, divisible by 8 -> bijective):
  const int lin = blockIdx.y * gridDim.x + blockIdx.x;
  const int nwg = gridDim.x * gridDim.y;
  const int wg = (lin & 7) * (nwg >> 3) + (lin >> 3);
  const int n0 = (wg & 1) * TBN;
  const size_t m0 = (size_t)(wg >> 1) * TBM;

  const int srow = tid >> 2;                              // 0..127
  const int schunk = ((tid & 3) ^ ((tid >> 3) & 3)) * 8;  // parity-key swizzled

  f32x4 acc[4][4] = {};

  const int rsel = lane & 15;
  const int g = lane >> 4;
  const int ch = (g ^ ((rsel >> 1) & 3)) * 8;  // swizzled chunk offset

#define STAGE(bufA, bufB, kt)                                                    \
  {                                                                              \
    const int k0_ = (kt) * TBK;                                                  \
    gload16(A + (m0 + srow) * D + k0_ + schunk, &(bufA)[tid * 8]);               \
    gload16(BT + (size_t)(n0 + srow) * D + k0_ + schunk, &(bufB)[tid * 8]);      \
    gload16(BT + (size_t)(n0 + 128 + srow) * D + k0_ + schunk,                   \
            &(bufB)[(512 + tid) * 8]);                                           \
  }

#define COMPUTE(bufA, bufB)                                                      \
  {                                                                              \
    __builtin_amdgcn_s_setprio(1);                                               \
    bf16x8 af_[4], bf_[4];                                                       \
    _Pragma("unroll") for (int j_ = 0; j_ < 4; ++j_)                             \
        bf_[j_] = *(const bf16x8*)&(bufB)[(wc * 64 + j_ * 16 + rsel) * TBK + ch];\
    _Pragma("unroll") for (int i_ = 0; i_ < 4; ++i_)                             \
        af_[i_] = *(const bf16x8*)&(bufA)[(wr * 64 + i_ * 16 + rsel) * TBK + ch];\
    _Pragma("unroll") for (int i_ = 0; i_ < 4; ++i_)                             \
        _Pragma("unroll") for (int j_ = 0; j_ < 4; ++j_)                         \
            acc[i_][j_] = __builtin_amdgcn_mfma_f32_16x16x32_bf16(               \
                af_[i_], bf_[j_], acc[i_][j_], 0, 0, 0);                         \
    __builtin_amdgcn_s_setprio(0);                                               \
  }

#define VMW(N)                                              \
  asm volatile("s_waitcnt vmcnt(" #N ")" ::: "memory");     \
  __builtin_amdgcn_sched_barrier(0)
#define BAR() __builtin_amdgcn_s_barrier()

  // K=512 -> 16 K-tiles; buffer b = tile%3; 2-tile-ahead, counted vmcnt.
  STAGE(lA0, lB0, 0); STAGE(lA1, lB1, 1); STAGE(lA2, lB2, 2);
  VMW(6); BAR(); COMPUTE(lA0, lB0); BAR(); STAGE(lA0, lB0, 3);   // t=0
  VMW(6); BAR(); COMPUTE(lA1, lB1); BAR(); STAGE(lA1, lB1, 4);   // t=1
  VMW(6); BAR(); COMPUTE(lA2, lB2); BAR(); STAGE(lA2, lB2, 5);   // t=2
  VMW(6); BAR(); COMPUTE(lA0, lB0); BAR(); STAGE(lA0, lB0, 6);   // t=3
  VMW(6); BAR(); COMPUTE(lA1, lB1); BAR(); STAGE(lA1, lB1, 7);   // t=4
  VMW(6); BAR(); COMPUTE(lA2, lB2); BAR(); STAGE(lA2, lB2, 8);   // t=5
  VMW(6); BAR(); COMPUTE(lA0, lB0); BAR(); STAGE(lA0, lB0, 9);   // t=6
  VMW(6); BAR(); COMPUTE(lA1, lB1); BAR(); STAGE(lA1, lB1, 10);  // t=7
  VMW(6); BAR(); COMPUTE(lA2, lB2); BAR(); STAGE(lA2, lB2, 11);  // t=8
  VMW(6); BAR(); COMPUTE(lA0, lB0); BAR(); STAGE(lA0, lB0, 12);  // t=9
  VMW(6); BAR(); COMPUTE(lA1, lB1); BAR(); STAGE(lA1, lB1, 13);  // t=10
  VMW(6); BAR(); COMPUTE(lA2, lB2); BAR(); STAGE(lA2, lB2, 14);  // t=11
  VMW(6); BAR(); COMPUTE(lA0, lB0); BAR(); STAGE(lA0, lB0, 15);  // t=12
  VMW(6); BAR(); COMPUTE(lA1, lB1); BAR();                       // t=13
  VMW(3); BAR(); COMPUTE(lA2, lB2); BAR();                       // t=14
  VMW(0); BAR(); COMPUTE(lA0, lB0);                              // t=15
#undef STAGE
#undef COMPUTE
#undef VMW
#undef BAR

  __syncthreads();  // drain before epilogue reuses smem

  // ---- epilogue via two LDS half-tiles [64][CPAD] bf16 (33.8 KB) ----
  // C/D layout: col=lane&15, row=(lane>>4)*4+reg (m89-verified)
  const int rbase = g * 4;
#pragma unroll
  for (int h = 0; h < 2; ++h) {
    if (wr == h) {
#pragma unroll
      for (int j = 0; j < 4; ++j) {
        const int col = wc * 64 + j * 16 + rsel;
        const float bv = bias[n0 + col];
#pragma unroll
        for (int i = 0; i < 4; ++i) {
#pragma unroll
          for (int q = 0; q < 4; ++q) {
            const int lrow = i * 16 + rbase + q;  // 0..63
            float v = acc[i][j][q] + bv;
            v = (v > 0.f) ? v : 0.01f * v;
            smem[lrow * CPAD + col] = f2b(v);
          }
        }
      }
    }
    __syncthreads();
    // cooperative store: 64 rows x 512B contiguous
#pragma unroll
    for (int it = 0; it < 4; ++it) {
      const int slot = it * 512 + tid;  // 2048 slots
      const int row = slot >> 5;
      const int chunk = slot & 31;
      const uint4 vv = *(const uint4*)&smem[row * CPAD + chunk * 8];
      const size_t grow = m0 + h * 64 + row;
      if (Obf) *(uint4*)(Obf + grow * D + n0 + chunk * 8) = vv;
      if (Of32) {
        float4 f0, f1;
        f0.x = b_lo(vv.x); f0.y = b_hi(vv.x); f0.z = b_lo(vv.y); f0.w = b_hi(vv.y);
        f1.x = b_lo(vv.z); f1.y = b_hi(vv.z); f1.z = b_lo(vv.w); f1.w = b_hi(vv.w);
        float* op = Of32 + grow * D + n0 + chunk * 8;
        *(float4*)op = f0;
        *(float4*)(op + 4) = f1;
      }
    }
    // fused segment-max over this half-tile (still resident in LDS)
    if (mvstage) {
      const int col = tid & 255;          // 0..255 within n0 slice
      const int rh = tid >> 8;            // 0/1: rows rh*32..rh*32+31
      const size_t rowbase = m0 + h * 64 + rh * 32;
      float mx = -3.4e38f;
      int curg = batch[rowbase];
#pragma unroll 4
      for (int r = 0; r < 32; ++r) {
        const int gg = batch[rowbase + r];
        if (gg != curg) {
          atomicMax(&mvstage[(size_t)curg * D + n0 + col], encf(mx));
          mx = -3.4e38f;
          curg = gg;
        }
        mx = fmaxf(mx, b_lo((uint)smem[(rh * 32 + r) * CPAD + col]));
      }
      atomicMax(&mvstage[(size_t)curg * D + n0 + col], encf(mx));
    }
    __syncthreads();
  }
}

// ------------- pool projection, split-K (R10-verified); mv is ENCODED ------
__global__ __launch_bounds__(256) void pool_partial(
    const uint* __restrict__ mv, const float* __restrict__ proj_w,
    const float* __restrict__ pool_w, float* __restrict__ pp) {
  const int g = blockIdx.x;                      // 64
  const int o = blockIdx.y * 256 + threadIdx.x;  // 2 x 256
  const int s = blockIdx.z >> 2, kq = blockIdx.z & 3;
  const float* W = (s == 0) ? proj_w : pool_w + (size_t)(s - 1) * D * D;
  const uint* m = mv + ((size_t)s * 64 + g) * D + kq * 128;
  const float* Wp = W + (size_t)(kq * 128) * D + o;
  float acc = 0.f;
#pragma unroll 8
  for (int k = 0; k < 128; ++k) acc = fmaf(decf(m[k]), Wp[(size_t)k * D], acc);
  pp[((size_t)blockIdx.z * 64 + g) * D + o] = acc;
}

__global__ __launch_bounds__(256) void pool_reduce(
    const float* __restrict__ pp, const float* __restrict__ proj_b,
    const float* __restrict__ pool_b, float* __restrict__ part) {
  const int i = blockIdx.x * 256 + threadIdx.x;  // < 64*512
  const int g = i >> 9, o = i & (D - 1);
  float acc = proj_b[o] + pool_b[o] + pool_b[D + o] + pool_b[2 * D + o];
#pragma unroll
  for (int s = 0; s < 16; ++s) acc += pp[((size_t)s * 64 + g) * D + o];
  part[i] = acc;
}

// ---------------------------------------------------------------------------
extern "C" void kernel_launch(void* const* d_in, const int* in_sizes, int n_in,
                              void* d_out, int out_size, void* d_ws, size_t ws_size,
                              hipStream_t stream) {
  const float* x = (const float*)d_in[0];
  const int* ei = (const int*)d_in[1];
  const int* batch = (const int*)d_in[2];
  const float* proj_w = (const float*)d_in[3];
  const float* proj_b = (const float*)d_in[4];
  const float* lin1_w = (const float*)d_in[5];
  const float* lin1_b = (const float*)d_in[6];
  const float* lin2_w = (const float*)d_in[7];
  const float* lin2_b = (const float*)d_in[8];
  const float* eps = (const float*)d_in[9];
  const float* pool_w = (const float*)d_in[10];
  const float* pool_b = (const float*)d_in[11];

  const int N = in_sizes[0] / D;  // 65536
  const int E = in_sizes[1] / 2;  // 524288
  const int B = 64;
  const int* src = ei;
  const int* dst = ei + E;

  float* part = (float*)d_out;         // [64][512]
  float* xout = part + (size_t)B * D;  // [N][512]

  // workspace carve (~212 MB)
  char* w = (char*)d_ws;
  ushort* xb = (ushort*)w;   w += (size_t)N * D * 2;
  ushort* hb = (ushort*)w;   w += (size_t)N * D * 2;
  ushort* tb = (ushort*)w;   w += (size_t)N * D * 2;
  ushort* l1bt = (ushort*)w; w += (size_t)3 * D * D * 2;
  ushort* l2bt = (ushort*)w; w += (size_t)3 * D * D * 2;
  int* rowptr = (int*)w;     w += (size_t)(N + 4) * 4;
  int* cursor = (int*)w;     w += (size_t)N * 4;
  int* deg = (int*)w;        w += (size_t)N * 4;
  int* csr = (int*)w;        w += (size_t)E * 4;
  int* bsum = (int*)w;       w += 256 * 4;
  int* gstart = (int*)w;     w += 128 * 4;
  uint* mvall = (uint*)w;     w += (size_t)4 * B * D * 4;   // [4][64][512] encoded
  float* pp = (float*)w;      w += (size_t)16 * B * D * 4;  // [16][64][512]
  (void)ws_size; (void)n_in; (void)out_size; (void)gstart;

  (void)hipMemsetAsync(deg, 0, (size_t)N * 4, stream);
  (void)hipMemsetAsync(mvall, 0, (size_t)4 * B * D * 4, stream);
  // convert + fused stage-0 segmax (re-gridded: 1024 x 512)
  f32_to_bf16_segmax<<<N / 64, 512, 0, stream>>>(x, xb, batch, mvall);
  transpose_all<<<dim3(8, 8, 6), 256, 0, stream>>>(lin1_w, lin2_w, l1bt, l2bt);
  count_deg<<<(E + 255) / 256, 256, 0, stream>>>(dst, deg, E);
  scan_block<<<N / 256, 256, 0, stream>>>(deg, rowptr, bsum);
  scan_block<<<1, 256, 0, stream>>>(bsum, bsum, (int*)nullptr);
  scan_fixup<<<N / 256, 256, 0, stream>>>(rowptr, bsum, cursor, N, E);
  fill_csr<<<(E + 255) / 256, 256, 0, stream>>>(src, dst, cursor, csr, E);

  for (int l = 0; l < 3; ++l) {
    agg_kernel<<<N / 4, 256, 0, stream>>>(xb, rowptr, csr, eps, l, hb);
    gemm_bias_leaky<<<dim3(D / TBN, N / TBM), 512, 0, stream>>>(
        hb, l1bt + (size_t)l * D * D, lin1_b + (size_t)l * D, tb, nullptr,
        batch, nullptr);
    gemm_bias_leaky<<<dim3(D / TBN, N / TBM), 512, 0, stream>>>(
        tb, l2bt + (size_t)l * D * D, lin2_b + (size_t)l * D,
        (l == 2) ? nullptr : xb,            // last layer: xb is dead, skip 67MB write
        (l == 2) ? xout : nullptr, batch,
        mvall + (size_t)(l + 1) * B * D);   // fused segmax stage l+1
  }

  // split-K pool projection (decodes mvall)
  pool_partial<<<dim3(B, 2, 16), 256, 0, stream>>>(mvall, proj_w, pool_w, pp);
  pool_reduce<<<B * D / 256, 256, 0, stream>>>(pp, proj_b, pool_b, part);
}

// Round 18
// 706.273 us; speedup vs baseline: 1.2147x; 1.0172x over previous
//
#include <hip/hip_runtime.h>

typedef unsigned int uint;
typedef unsigned short ushort;

#define D 512
#define TBM 128   // M-tile
#define TBN 256   // N-tile
#define TBK 32    // K-step
#define CPAD 264  // padded C-tile row (ushorts)

typedef __attribute__((ext_vector_type(8))) short bf16x8;
typedef __attribute__((ext_vector_type(4))) float f32x4;

__device__ __forceinline__ ushort f2b(float f) {
  uint u = __builtin_bit_cast(uint, f);
  return (ushort)((u + 0x7FFFu + ((u >> 16) & 1u)) >> 16);  // RNE
}
__device__ __forceinline__ float b_lo(uint u) { return __builtin_bit_cast(float, u << 16); }
__device__ __forceinline__ float b_hi(uint u) { return __builtin_bit_cast(float, u & 0xFFFF0000u); }

// monotone float<->uint map: uint order == float order (for max via atomicMax)
__device__ __forceinline__ uint encf(float x) {
  uint u = __builtin_bit_cast(uint, x);
  return ((int)u >= 0) ? (u | 0x80000000u) : ~u;
}
__device__ __forceinline__ float decf(uint u) {
  return (u & 0x80000000u) ? __builtin_bit_cast(float, u ^ 0x80000000u)
                           : __builtin_bit_cast(float, ~u);
}

__device__ __forceinline__ void gload16(const void* g, void* l) {
  __builtin_amdgcn_global_load_lds((const __attribute__((address_space(1))) void*)g,
                                   (__attribute__((address_space(3))) void*)l, 16, 0, 0);
}

// ==== mega prologue: [convert+segmax | count_deg | transpose] roles ========
// R18: count_deg (atomic/latency-bound) and transpose (tiny) are independent
// of the convert (BW-bound) — run them as separate-role blocks in ONE grid so
// they hide under the convert's memory time (m114 overlap; roles are
// light-register + small-LDS so no occupancy interference, unlike R16).
__global__ __launch_bounds__(512) void mega_prolog(
    const float* __restrict__ x, ushort* __restrict__ xb,
    const int* __restrict__ batch, uint* __restrict__ mv0,
    const int* __restrict__ dst, int* __restrict__ deg, int E,
    const float* __restrict__ lin1_w, const float* __restrict__ lin2_w,
    ushort* __restrict__ l1bt, ushort* __restrict__ l2bt) {
  __shared__ union {
    uint red[8 * 512];      // convert role (16 KB)
    float tile[64][65];     // transpose role (16.25 KB)
  } sm;
  const int bid = blockIdx.x;
  const int t = threadIdx.x;

  if (bid < 1024) {
    // ---- role A: f32->bf16 convert + fused stage-0 segmax (R17-verified) --
    const int chunk = t & 63;
    const int rsub = t >> 6;
    const int row0 = bid * 64;
    const bool uni = (batch[row0] == batch[row0 + 63]);  // sorted batch
    float mx[8];
#pragma unroll
    for (int j = 0; j < 8; ++j) mx[j] = -3.4e38f;
    int curg = batch[row0 + rsub];
#pragma unroll
    for (int k = 0; k < 8; ++k) {
      const int row = row0 + rsub + k * 8;
      if (!uni) {
        const int gg = batch[row];
        if (gg != curg) {
#pragma unroll
          for (int j = 0; j < 8; ++j)
            atomicMax(&mv0[(size_t)curg * D + chunk * 8 + j], encf(mx[j]));
#pragma unroll
          for (int j = 0; j < 8; ++j) mx[j] = -3.4e38f;
          curg = gg;
        }
      }
      const float4* p = (const float4*)(x + (size_t)row * D + chunk * 8);
      const float4 a = p[0], b = p[1];
      float v[8] = {a.x, a.y, a.z, a.w, b.x, b.y, b.z, b.w};
      uint4 o;
      o.x = f2b(v[0]) | ((uint)f2b(v[1]) << 16);
      o.y = f2b(v[2]) | ((uint)f2b(v[3]) << 16);
      o.z = f2b(v[4]) | ((uint)f2b(v[5]) << 16);
      o.w = f2b(v[6]) | ((uint)f2b(v[7]) << 16);
      *(uint4*)(xb + (size_t)row * D + chunk * 8) = o;
#pragma unroll
      for (int j = 0; j < 8; ++j) mx[j] = fmaxf(mx[j], v[j]);
    }
    if (uni) {
      uint4 e0, e1;
      e0.x = encf(mx[0]); e0.y = encf(mx[1]); e0.z = encf(mx[2]); e0.w = encf(mx[3]);
      e1.x = encf(mx[4]); e1.y = encf(mx[5]); e1.z = encf(mx[6]); e1.w = encf(mx[7]);
      *(uint4*)&sm.red[rsub * 512 + chunk * 8] = e0;
      *(uint4*)&sm.red[rsub * 512 + chunk * 8 + 4] = e1;
      __syncthreads();
      uint m = sm.red[t];
#pragma unroll
      for (int r = 1; r < 8; ++r) m = max(m, sm.red[r * 512 + t]);
      atomicMax(&mv0[(size_t)curg * D + t], m);
    } else {
#pragma unroll
      for (int j = 0; j < 8; ++j)
        atomicMax(&mv0[(size_t)curg * D + chunk * 8 + j], encf(mx[j]));
    }
  } else if (bid < 2048) {
    // ---- role B: count_deg ----
    const int e = (bid - 1024) * 512 + t;
    if (e < E) atomicAdd(&deg[dst[e]], 1);
  } else {
    // ---- role C: weight transpose (512-thr variant) ----
    const int idx = bid - 2048;          // [0,384)
    const int z = idx >> 6, rem = idx & 63;
    const int l = z >> 1;
    const float* W = ((z & 1) ? lin2_w : lin1_w) + (size_t)l * D * D;
    ushort* BT = ((z & 1) ? l2bt : l1bt) + (size_t)l * D * D;
    const int bk = (rem >> 3) * 64;
    const int bo = (rem & 7) * 64;
    const int tx = t & 63, ty = t >> 6;  // ty 0..7
#pragma unroll
    for (int r = 0; r < 64; r += 8)
      sm.tile[r + ty][tx] = W[(size_t)(bk + r + ty) * D + bo + tx];
    __syncthreads();
#pragma unroll
    for (int r = 0; r < 64; r += 8)
      BT[(size_t)(bo + r + ty) * D + bk + tx] = f2b(sm.tile[tx][r + ty]);
  }
}

// ---------------------------- CSR build ------------------------------------
__global__ __launch_bounds__(256) void scan_block(const int* __restrict__ in,
                                                  int* __restrict__ out,
                                                  int* __restrict__ bsum) {
  __shared__ int sm[256];
  const int t = threadIdx.x;
  const int gi = blockIdx.x * 256 + t;
  const int v = in[gi];
  int x = v;
  sm[t] = x;
  __syncthreads();
#pragma unroll
  for (int off = 1; off < 256; off <<= 1) {
    const int y = (t >= off) ? sm[t - off] : 0;
    __syncthreads();
    x += y;
    sm[t] = x;
    __syncthreads();
  }
  out[gi] = x - v;  // exclusive
  if (t == 255 && bsum) bsum[blockIdx.x] = x;
}

__global__ void scan_fixup(int* __restrict__ rowptr, const int* __restrict__ bsum,
                           int* __restrict__ cursor, int N, int E) {
  const int i = blockIdx.x * 256 + threadIdx.x;
  const int r = rowptr[i] + bsum[i >> 8];
  rowptr[i] = r;
  cursor[i] = r;
  if (i == 0) rowptr[N] = E;
}

__global__ void fill_csr(const int* __restrict__ src, const int* __restrict__ dst,
                         int* __restrict__ cursor, int* __restrict__ csr, int E) {
  const int e = blockIdx.x * 256 + threadIdx.x;
  if (e >= E) return;
  const int pos = atomicAdd(&cursor[dst[e]], 1);
  csr[pos] = src[e];
}

// --------------- GIN aggregation: h = (1+eps)*x + sum_nbr x ----------------
// At its delivered-bytes floor (~604MB at ~6.4TB/s effective; R2/R4/R7/R16).
#define ACC8(v)                                          \
  a[0] += b_lo((v).x); a[1] += b_hi((v).x);              \
  a[2] += b_lo((v).y); a[3] += b_hi((v).y);              \
  a[4] += b_lo((v).z); a[5] += b_hi((v).z);              \
  a[6] += b_lo((v).w); a[7] += b_hi((v).w)

__global__ __launch_bounds__(256) void agg_kernel(const ushort* __restrict__ xb,
                                                  const int* __restrict__ rowptr,
                                                  const int* __restrict__ csr,
                                                  const float* __restrict__ eps_arr,
                                                  int layer, ushort* __restrict__ h) {
  const int node = blockIdx.x * 4 + (threadIdx.x >> 6);
  const int lane = threadIdx.x & 63;
  const float sc = 1.0f + eps_arr[layer];
  const size_t off = (size_t)lane * 8;
  const size_t base = (size_t)node * D + off;
  const uint4 u = *(const uint4*)(xb + base);
  float a[8];
  a[0] = b_lo(u.x) * sc; a[1] = b_hi(u.x) * sc;
  a[2] = b_lo(u.y) * sc; a[3] = b_hi(u.y) * sc;
  a[4] = b_lo(u.z) * sc; a[5] = b_hi(u.z) * sc;
  a[6] = b_lo(u.w) * sc; a[7] = b_hi(u.w) * sc;
  int e = rowptr[node];
  const int en = rowptr[node + 1];
  for (; e + 4 <= en; e += 4) {
    const int s0 = csr[e], s1 = csr[e + 1], s2 = csr[e + 2], s3 = csr[e + 3];
    const uint4 v0 = *(const uint4*)(xb + (size_t)s0 * D + off);
    const uint4 v1 = *(const uint4*)(xb + (size_t)s1 * D + off);
    const uint4 v2 = *(const uint4*)(xb + (size_t)s2 * D + off);
    const uint4 v3 = *(const uint4*)(xb + (size_t)s3 * D + off);
    ACC8(v0); ACC8(v1); ACC8(v2); ACC8(v3);
  }
  if (e + 2 <= en) {
    const int s0 = csr[e], s1 = csr[e + 1];
    const uint4 v0 = *(const uint4*)(xb + (size_t)s0 * D + off);
    const uint4 v1 = *(const uint4*)(xb + (size_t)s1 * D + off);
    ACC8(v0); ACC8(v1);
    e += 2;
  }
  if (e < en) {
    const uint4 v0 = *(const uint4*)(xb + (size_t)csr[e] * D + off);
    ACC8(v0);
  }
  uint4 o;
  o.x = f2b(a[0]) | ((uint)f2b(a[1]) << 16);
  o.y = f2b(a[2]) | ((uint)f2b(a[3]) << 16);
  o.z = f2b(a[4]) | ((uint)f2b(a[5]) << 16);
  o.w = f2b(a[6]) | ((uint)f2b(a[7]) << 16);
  *(uint4*)(h + base) = o;
}

// ------ bf16 GEMM: O = leaky(A @ BT^T + bias), 128x256 tile, BK=32 ---------
// R15-verified: 2 blocks/CU, 3-buffer 2-ahead counted vmcnt, parity-correct
// chunk-XOR swizzle (key (rsel>>1)&3 both sides), padded-LDS epilogue,
// nullable Obf/Of32, fused segmax.
__global__ __launch_bounds__(512, 4) void gemm_bias_leaky(
    const ushort* __restrict__ A, const ushort* __restrict__ BT,
    const float* __restrict__ bias, ushort* __restrict__ Obf,
    float* __restrict__ Of32, const int* __restrict__ batch,
    uint* __restrict__ mvstage) {
  __shared__ alignas(16) ushort smem[36864];  // 72 KB
  ushort* const lA0 = smem;            // [128][32]  4096
  ushort* const lB0 = smem + 4096;     // [256][32]  8192
  ushort* const lA1 = smem + 12288;
  ushort* const lB1 = smem + 16384;
  ushort* const lA2 = smem + 24576;
  ushort* const lB2 = smem + 28672;

  const int tid = threadIdx.x;
  const int lane = tid & 63;
  const int wave = tid >> 6;
  const int wr = wave >> 2, wc = wave & 3;  // 2x4 waves; 64x64 out each

  // XCD swizzle (nwg = 2*512 = 1024, divisible by 8 -> bijective):
  const int lin = blockIdx.y * gridDim.x + blockIdx.x;
  const int nwg = gridDim.x * gridDim.y;
  const int wg = (lin & 7) * (nwg >> 3) + (lin >> 3);
  const int n0 = (wg & 1) * TBN;
  const size_t m0 = (size_t)(wg >> 1) * TBM;

  const int srow = tid >> 2;                              // 0..127
  const int schunk = ((tid & 3) ^ ((tid >> 3) & 3)) * 8;  // parity-key swizzled

  f32x4 acc[4][4] = {};

  const int rsel = lane & 15;
  const int g = lane >> 4;
  const int ch = (g ^ ((rsel >> 1) & 3)) * 8;  // swizzled chunk offset

#define STAGE(bufA, bufB, kt)                                                    \
  {                                                                              \
    const int k0_ = (kt) * TBK;                                                  \
    gload16(A + (m0 + srow) * D + k0_ + schunk, &(bufA)[tid * 8]);               \
    gload16(BT + (size_t)(n0 + srow) * D + k0_ + schunk, &(bufB)[tid * 8]);      \
    gload16(BT + (size_t)(n0 + 128 + srow) * D + k0_ + schunk,                   \
            &(bufB)[(512 + tid) * 8]);                                           \
  }

#define COMPUTE(bufA, bufB)                                                      \
  {                                                                              \
    __builtin_amdgcn_s_setprio(1);                                               \
    bf16x8 af_[4], bf_[4];                                                       \
    _Pragma("unroll") for (int j_ = 0; j_ < 4; ++j_)                             \
        bf_[j_] = *(const bf16x8*)&(bufB)[(wc * 64 + j_ * 16 + rsel) * TBK + ch];\
    _Pragma("unroll") for (int i_ = 0; i_ < 4; ++i_)                             \
        af_[i_] = *(const bf16x8*)&(bufA)[(wr * 64 + i_ * 16 + rsel) * TBK + ch];\
    _Pragma("unroll") for (int i_ = 0; i_ < 4; ++i_)                             \
        _Pragma("unroll") for (int j_ = 0; j_ < 4; ++j_)                         \
            acc[i_][j_] = __builtin_amdgcn_mfma_f32_16x16x32_bf16(               \
                af_[i_], bf_[j_], acc[i_][j_], 0, 0, 0);                         \
    __builtin_amdgcn_s_setprio(0);                                               \
  }

#define VMW(N)                                              \
  asm volatile("s_waitcnt vmcnt(" #N ")" ::: "memory");     \
  __builtin_amdgcn_sched_barrier(0)
#define BAR() __builtin_amdgcn_s_barrier()

  // K=512 -> 16 K-tiles; buffer b = tile%3; 2-tile-ahead, counted vmcnt.
  STAGE(lA0, lB0, 0); STAGE(lA1, lB1, 1); STAGE(lA2, lB2, 2);
  VMW(6); BAR(); COMPUTE(lA0, lB0); BAR(); STAGE(lA0, lB0, 3);   // t=0
  VMW(6); BAR(); COMPUTE(lA1, lB1); BAR(); STAGE(lA1, lB1, 4);   // t=1
  VMW(6); BAR(); COMPUTE(lA2, lB2); BAR(); STAGE(lA2, lB2, 5);   // t=2
  VMW(6); BAR(); COMPUTE(lA0, lB0); BAR(); STAGE(lA0, lB0, 6);   // t=3
  VMW(6); BAR(); COMPUTE(lA1, lB1); BAR(); STAGE(lA1, lB1, 7);   // t=4
  VMW(6); BAR(); COMPUTE(lA2, lB2); BAR(); STAGE(lA2, lB2, 8);   // t=5
  VMW(6); BAR(); COMPUTE(lA0, lB0); BAR(); STAGE(lA0, lB0, 9);   // t=6
  VMW(6); BAR(); COMPUTE(lA1, lB1); BAR(); STAGE(lA1, lB1, 10);  // t=7
  VMW(6); BAR(); COMPUTE(lA2, lB2); BAR(); STAGE(lA2, lB2, 11);  // t=8
  VMW(6); BAR(); COMPUTE(lA0, lB0); BAR(); STAGE(lA0, lB0, 12);  // t=9
  VMW(6); BAR(); COMPUTE(lA1, lB1); BAR(); STAGE(lA1, lB1, 13);  // t=10
  VMW(6); BAR(); COMPUTE(lA2, lB2); BAR(); STAGE(lA2, lB2, 14);  // t=11
  VMW(6); BAR(); COMPUTE(lA0, lB0); BAR(); STAGE(lA0, lB0, 15);  // t=12
  VMW(6); BAR(); COMPUTE(lA1, lB1); BAR();                       // t=13
  VMW(3); BAR(); COMPUTE(lA2, lB2); BAR();                       // t=14
  VMW(0); BAR(); COMPUTE(lA0, lB0);                              // t=15
#undef STAGE
#undef COMPUTE
#undef VMW
#undef BAR

  __syncthreads();  // drain before epilogue reuses smem

  // ---- epilogue via two LDS half-tiles [64][CPAD] bf16 (33.8 KB) ----
  // C/D layout: col=lane&15, row=(lane>>4)*4+reg (m89-verified)
  const int rbase = g * 4;
#pragma unroll
  for (int h = 0; h < 2; ++h) {
    if (wr == h) {
#pragma unroll
      for (int j = 0; j < 4; ++j) {
        const int col = wc * 64 + j * 16 + rsel;
        const float bv = bias[n0 + col];
#pragma unroll
        for (int i = 0; i < 4; ++i) {
#pragma unroll
          for (int q = 0; q < 4; ++q) {
            const int lrow = i * 16 + rbase + q;  // 0..63
            float v = acc[i][j][q] + bv;
            v = (v > 0.f) ? v : 0.01f * v;
            smem[lrow * CPAD + col] = f2b(v);
          }
        }
      }
    }
    __syncthreads();
    // cooperative store: 64 rows x 512B contiguous
#pragma unroll
    for (int it = 0; it < 4; ++it) {
      const int slot = it * 512 + tid;  // 2048 slots
      const int row = slot >> 5;
      const int chunk = slot & 31;
      const uint4 vv = *(const uint4*)&smem[row * CPAD + chunk * 8];
      const size_t grow = m0 + h * 64 + row;
      if (Obf) *(uint4*)(Obf + grow * D + n0 + chunk * 8) = vv;
      if (Of32) {
        float4 f0, f1;
        f0.x = b_lo(vv.x); f0.y = b_hi(vv.x); f0.z = b_lo(vv.y); f0.w = b_hi(vv.y);
        f1.x = b_lo(vv.z); f1.y = b_hi(vv.z); f1.z = b_lo(vv.w); f1.w = b_hi(vv.w);
        float* op = Of32 + grow * D + n0 + chunk * 8;
        *(float4*)op = f0;
        *(float4*)(op + 4) = f1;
      }
    }
    // fused segment-max over this half-tile (still resident in LDS)
    if (mvstage) {
      const int col = tid & 255;          // 0..255 within n0 slice
      const int rh = tid >> 8;            // 0/1: rows rh*32..rh*32+31
      const size_t rowbase = m0 + h * 64 + rh * 32;
      float mx = -3.4e38f;
      int curg = batch[rowbase];
#pragma unroll 4
      for (int r = 0; r < 32; ++r) {
        const int gg = batch[rowbase + r];
        if (gg != curg) {
          atomicMax(&mvstage[(size_t)curg * D + n0 + col], encf(mx));
          mx = -3.4e38f;
          curg = gg;
        }
        mx = fmaxf(mx, b_lo((uint)smem[(rh * 32 + r) * CPAD + col]));
      }
      atomicMax(&mvstage[(size_t)curg * D + n0 + col], encf(mx));
    }
    __syncthreads();
  }
}

// ------------- pool projection, split-K (R10-verified); mv is ENCODED ------
__global__ __launch_bounds__(256) void pool_partial(
    const uint* __restrict__ mv, const float* __restrict__ proj_w,
    const float* __restrict__ pool_w, float* __restrict__ pp) {
  const int g = blockIdx.x;                      // 64
  const int o = blockIdx.y * 256 + threadIdx.x;  // 2 x 256
  const int s = blockIdx.z >> 2, kq = blockIdx.z & 3;
  const float* W = (s == 0) ? proj_w : pool_w + (size_t)(s - 1) * D * D;
  const uint* m = mv + ((size_t)s * 64 + g) * D + kq * 128;
  const float* Wp = W + (size_t)(kq * 128) * D + o;
  float acc = 0.f;
#pragma unroll 8
  for (int k = 0; k < 128; ++k) acc = fmaf(decf(m[k]), Wp[(size_t)k * D], acc);
  pp[((size_t)blockIdx.z * 64 + g) * D + o] = acc;
}

__global__ __launch_bounds__(256) void pool_reduce(
    const float* __restrict__ pp, const float* __restrict__ proj_b,
    const float* __restrict__ pool_b, float* __restrict__ part) {
  const int i = blockIdx.x * 256 + threadIdx.x;  // < 64*512
  const int g = i >> 9, o = i & (D - 1);
  float acc = proj_b[o] + pool_b[o] + pool_b[D + o] + pool_b[2 * D + o];
#pragma unroll
  for (int s = 0; s < 16; ++s) acc += pp[((size_t)s * 64 + g) * D + o];
  part[i] = acc;
}

// ---------------------------------------------------------------------------
extern "C" void kernel_launch(void* const* d_in, const int* in_sizes, int n_in,
                              void* d_out, int out_size, void* d_ws, size_t ws_size,
                              hipStream_t stream) {
  const float* x = (const float*)d_in[0];
  const int* ei = (const int*)d_in[1];
  const int* batch = (const int*)d_in[2];
  const float* proj_w = (const float*)d_in[3];
  const float* proj_b = (const float*)d_in[4];
  const float* lin1_w = (const float*)d_in[5];
  const float* lin1_b = (const float*)d_in[6];
  const float* lin2_w = (const float*)d_in[7];
  const float* lin2_b = (const float*)d_in[8];
  const float* eps = (const float*)d_in[9];
  const float* pool_w = (const float*)d_in[10];
  const float* pool_b = (const float*)d_in[11];

  const int N = in_sizes[0] / D;  // 65536
  const int E = in_sizes[1] / 2;  // 524288
  const int B = 64;
  const int* src = ei;
  const int* dst = ei + E;

  float* part = (float*)d_out;         // [64][512]
  float* xout = part + (size_t)B * D;  // [N][512]

  // workspace carve (~212 MB)
  char* w = (char*)d_ws;
  ushort* xb = (ushort*)w;   w += (size_t)N * D * 2;
  ushort* hb = (ushort*)w;   w += (size_t)N * D * 2;
  ushort* tb = (ushort*)w;   w += (size_t)N * D * 2;
  ushort* l1bt = (ushort*)w; w += (size_t)3 * D * D * 2;
  ushort* l2bt = (ushort*)w; w += (size_t)3 * D * D * 2;
  int* rowptr = (int*)w;     w += (size_t)(N + 4) * 4;
  int* cursor = (int*)w;     w += (size_t)N * 4;
  int* deg = (int*)w;        w += (size_t)N * 4;
  int* csr = (int*)w;        w += (size_t)E * 4;
  int* bsum = (int*)w;       w += 256 * 4;
  int* gstart = (int*)w;     w += 128 * 4;
  uint* mvall = (uint*)w;     w += (size_t)4 * B * D * 4;   // [4][64][512] encoded
  float* pp = (float*)w;      w += (size_t)16 * B * D * 4;  // [16][64][512]
  (void)ws_size; (void)n_in; (void)out_size; (void)gstart;

  (void)hipMemsetAsync(deg, 0, (size_t)N * 4, stream);
  (void)hipMemsetAsync(mvall, 0, (size_t)4 * B * D * 4, stream);
  // convert+segmax || count_deg || weight transpose, one grid
  mega_prolog<<<2432, 512, 0, stream>>>(x, xb, batch, mvall, dst, deg, E,
                                        lin1_w, lin2_w, l1bt, l2bt);
  scan_block<<<N / 256, 256, 0, stream>>>(deg, rowptr, bsum);
  scan_block<<<1, 256, 0, stream>>>(bsum, bsum, (int*)nullptr);
  scan_fixup<<<N / 256, 256, 0, stream>>>(rowptr, bsum, cursor, N, E);
  fill_csr<<<(E + 255) / 256, 256, 0, stream>>>(src, dst, cursor, csr, E);

  for (int l = 0; l < 3; ++l) {
    agg_kernel<<<N / 4, 256, 0, stream>>>(xb, rowptr, csr, eps, l, hb);
    gemm_bias_leaky<<<dim3(D / TBN, N / TBM), 512, 0, stream>>>(
        hb, l1bt + (size_t)l * D * D, lin1_b + (size_t)l * D, tb, nullptr,
        batch, nullptr);
    gemm_bias_leaky<<<dim3(D / TBN, N / TBM), 512, 0, stream>>>(
        tb, l2bt + (size_t)l * D * D, lin2_b + (size_t)l * D,
        (l == 2) ? nullptr : xb,            // last layer: xb is dead, skip 67MB write
        (l == 2) ? xout : nullptr, batch,
        mvall + (size_t)(l + 1) * B * D);   // fused segmax stage l+1
  }

  // split-K pool projection (decodes mvall)
  pool_partial<<<dim3(B, 2, 16), 256, 0, stream>>>(mvall, proj_w, pool_w, pp);
  pool_reduce<<<B * D / 256, 256, 0, stream>>>(pp, proj_b, pool_b, part);
}